// Round 1
// baseline (455.790 us; speedup 1.0000x reference)
//
#include <hip/hip_runtime.h>

typedef unsigned short ushort_t;
typedef unsigned int uint_t;
typedef __attribute__((ext_vector_type(8))) short bf16x8;
typedef __attribute__((ext_vector_type(4))) float f32x4;

constexpr int L_   = 3;
constexpr int B_   = 8192;
constexpr int H_   = 1024;
constexpr int DIN_ = 1024;
constexpr int DOUT_= 80;
constexpr int NACT_= 4096;
constexpr int G3_  = 3 * H_;

static __device__ __forceinline__ ushort_t f2bf(float f) {
    uint_t u = __float_as_uint(f);
    uint_t r = (u + 0x7FFFu + ((u >> 16) & 1u)) >> 16;
    return (ushort_t)r;
}

// ---------------- prep: convert weights fp32 -> bf16 ----------------
__global__ void prep_convert(const float* __restrict__ wih, const float* __restrict__ whh,
                             const float* __restrict__ wout,
                             ushort_t* __restrict__ oih, ushort_t* __restrict__ ohh,
                             ushort_t* __restrict__ oout) {
    int tid = blockIdx.x * blockDim.x + threadIdx.x;
    int nth = gridDim.x * blockDim.x;
    const int NW = L_ * G3_ * H_ / 4;
    for (int i = tid; i < NW; i += nth) {
        float4 a = ((const float4*)wih)[i];
        ushort4 o; o.x = f2bf(a.x); o.y = f2bf(a.y); o.z = f2bf(a.z); o.w = f2bf(a.w);
        ((ushort4*)oih)[i] = o;
        float4 b = ((const float4*)whh)[i];
        ushort4 p; p.x = f2bf(b.x); p.y = f2bf(b.y); p.z = f2bf(b.z); p.w = f2bf(b.w);
        ((ushort4*)ohh)[i] = p;
    }
    const int NO = DOUT_ * H_ / 4;
    for (int i = tid; i < NO; i += nth) {
        float4 a = ((const float4*)wout)[i];
        ushort4 o; o.x = f2bf(a.x); o.y = f2bf(a.y); o.z = f2bf(a.z); o.w = f2bf(a.w);
        ((ushort4*)oout)[i] = o;
    }
}

// ---------------- prep: gather x0 = encoded[idx], h_b16[l] = hidden[l][idx] ----------------
__global__ void prep_gather(const float* __restrict__ encoded, const float* __restrict__ hidden,
                            const int* __restrict__ idx,
                            ushort_t* __restrict__ x0, ushort_t* __restrict__ hb) {
    const int C4 = H_ / 4;              // 256 float4 per row
    const int PER = NACT_ * C4;         // per segment
    int tid = blockIdx.x * blockDim.x + threadIdx.x;
    int nth = gridDim.x * blockDim.x;
    int total = 4 * PER;                // seg0 = x, seg1..3 = h layers
    for (int i = tid; i < total; i += nth) {
        int seg = i / PER;
        int rem = i - seg * PER;
        int r = rem / C4, c = rem % C4;
        int gr = idx[r];
        const float* src = (seg == 0) ? (encoded + (size_t)gr * DIN_)
                                      : (hidden + ((size_t)(seg - 1) * B_ + gr) * H_);
        float4 v = ((const float4*)src)[c];
        ushort4 o; o.x = f2bf(v.x); o.y = f2bf(v.y); o.z = f2bf(v.z); o.w = f2bf(v.w);
        ushort_t* dst = (seg == 0) ? x0 : (hb + (size_t)(seg - 1) * NACT_ * H_);
        ((ushort4*)(dst + (size_t)r * H_))[c] = o;
    }
}

// ---------------- fused GRU layer: 4-accumulator GEMM + gate epilogue ----------------
// acc_r = [x|h] @ [wih_r|whh_r]^T ; acc_z likewise ; acc_n[0]=x@wih_n^T ; acc_n[1]=h@whh_n^T
__global__ __launch_bounds__(256) void gru_layer(
    const ushort_t* __restrict__ xb,    // [N,H] bf16 layer input
    const ushort_t* __restrict__ hb,    // [N,H] bf16 gathered hidden
    const float* __restrict__ hid_full, // [B,H] fp32 hidden[i]
    const ushort_t* __restrict__ wih,   // [3H,H] bf16
    const ushort_t* __restrict__ whh,   // [3H,H] bf16
    const float* __restrict__ bih, const float* __restrict__ bhh,
    const int* __restrict__ idx,
    float* __restrict__ out_hid,        // [B,H] fp32 (pre-copied)
    ushort_t* __restrict__ xnext)       // [N,H] bf16
{
    __shared__ ushort_t As[64][72];
    __shared__ ushort_t Bs[3][64][72];
    const int tid = threadIdx.x;
    const int bn = blockIdx.x;          // 0..15 col tiles
    const int bm = blockIdx.y;          // 0..63 row tiles
    const int row0 = bm * 64, col0 = bn * 64;
    const int lrow = tid >> 2, lseg = tid & 3;      // staging: row, 16-elem segment
    const int wave = tid >> 6, lane = tid & 63;
    const int wr = wave >> 1, wc = wave & 1;
    const int fl = lane & 15, fh = lane >> 4;

    f32x4 acc_r[2][2] = {};
    f32x4 acc_z[2][2] = {};
    f32x4 acc_n[2][2][2] = {};          // [phase][m][n]

#pragma unroll
    for (int ph = 0; ph < 2; ++ph) {
        const ushort_t* Asrc = ph ? hb : xb;
        const ushort_t* Wsrc = ph ? whh : wih;
        for (int kk = 0; kk < H_; kk += 64) {
            __syncthreads();
            const ushort_t* ap = Asrc + (size_t)(row0 + lrow) * H_ + kk + lseg * 16;
            *(uint4*)&As[lrow][lseg * 16]     = *(const uint4*)ap;
            *(uint4*)&As[lrow][lseg * 16 + 8] = *(const uint4*)(ap + 8);
#pragma unroll
            for (int s = 0; s < 3; ++s) {
                const ushort_t* bp = Wsrc + (size_t)(s * H_ + col0 + lrow) * H_ + kk + lseg * 16;
                *(uint4*)&Bs[s][lrow][lseg * 16]     = *(const uint4*)bp;
                *(uint4*)&Bs[s][lrow][lseg * 16 + 8] = *(const uint4*)(bp + 8);
            }
            __syncthreads();
#pragma unroll
            for (int ks = 0; ks < 64; ks += 32) {
                bf16x8 a[2], b[3][2];
#pragma unroll
                for (int m = 0; m < 2; ++m)
                    a[m] = *(const bf16x8*)&As[wr * 32 + m * 16 + fl][ks + fh * 8];
#pragma unroll
                for (int s = 0; s < 3; ++s)
#pragma unroll
                    for (int n = 0; n < 2; ++n)
                        b[s][n] = *(const bf16x8*)&Bs[s][wc * 32 + n * 16 + fl][ks + fh * 8];
#pragma unroll
                for (int m = 0; m < 2; ++m)
#pragma unroll
                    for (int n = 0; n < 2; ++n) {
                        acc_r[m][n] = __builtin_amdgcn_mfma_f32_16x16x32_bf16(a[m], b[0][n], acc_r[m][n], 0, 0, 0);
                        acc_z[m][n] = __builtin_amdgcn_mfma_f32_16x16x32_bf16(a[m], b[1][n], acc_z[m][n], 0, 0, 0);
                        acc_n[ph][m][n] = __builtin_amdgcn_mfma_f32_16x16x32_bf16(a[m], b[2][n], acc_n[ph][m][n], 0, 0, 0);
                    }
            }
        }
    }

    // epilogue: gate math, scatter into out_hid, write bf16 x for next layer
#pragma unroll
    for (int m = 0; m < 2; ++m) {
#pragma unroll
        for (int n = 0; n < 2; ++n) {
            const int c = col0 + wc * 32 + n * 16 + fl;
            const float br_r = bih[c] + bhh[c];
            const float br_z = bih[H_ + c] + bhh[H_ + c];
            const float bi_n = bih[2 * H_ + c];
            const float bh_n = bhh[2 * H_ + c];
#pragma unroll
            for (int j = 0; j < 4; ++j) {
                const int r = row0 + wr * 32 + m * 16 + fh * 4 + j;
                const float vr = 1.f / (1.f + expf(-(acc_r[m][n][j] + br_r)));
                const float vz = 1.f / (1.f + expf(-(acc_z[m][n][j] + br_z)));
                const float vn = tanhf(acc_n[0][m][n][j] + bi_n + vr * (acc_n[1][m][n][j] + bh_n));
                const int gr = idx[r];
                const float h0 = hid_full[(size_t)gr * H_ + c];
                const float ho = (1.f - vz) * vn + vz * h0;
                out_hid[(size_t)gr * H_ + c] = ho;
                xnext[(size_t)r * H_ + c] = f2bf(ho);
            }
        }
    }
}

// ---------------- head: y = tanh(x @ w_out^T + b_out), scatter ----------------
__global__ __launch_bounds__(256) void head_gemm(
    const ushort_t* __restrict__ xb, const ushort_t* __restrict__ wo,
    const float* __restrict__ bo, const int* __restrict__ idx,
    float* __restrict__ outy)
{
    __shared__ ushort_t Xs[64][72];
    __shared__ ushort_t Ws[80][72];
    const int tid = threadIdx.x;
    const int row0 = blockIdx.x * 64;
    const int lrow = tid >> 2, lseg = tid & 3;
    const int wave = tid >> 6, lane = tid & 63;
    const int fl = lane & 15, fh = lane >> 4;
    f32x4 acc[5] = {};

    for (int kk = 0; kk < H_; kk += 64) {
        __syncthreads();
        const ushort_t* xp = xb + (size_t)(row0 + lrow) * H_ + kk + lseg * 16;
        *(uint4*)&Xs[lrow][lseg * 16]     = *(const uint4*)xp;
        *(uint4*)&Xs[lrow][lseg * 16 + 8] = *(const uint4*)(xp + 8);
        for (int t = tid; t < 320; t += 256) {
            int r = t >> 2, s = t & 3;
            const ushort_t* wp = wo + (size_t)r * H_ + kk + s * 16;
            *(uint4*)&Ws[r][s * 16]     = *(const uint4*)wp;
            *(uint4*)&Ws[r][s * 16 + 8] = *(const uint4*)(wp + 8);
        }
        __syncthreads();
#pragma unroll
        for (int ks = 0; ks < 64; ks += 32) {
            bf16x8 a = *(const bf16x8*)&Xs[wave * 16 + fl][ks + fh * 8];
#pragma unroll
            for (int nf = 0; nf < 5; ++nf) {
                bf16x8 b = *(const bf16x8*)&Ws[nf * 16 + fl][ks + fh * 8];
                acc[nf] = __builtin_amdgcn_mfma_f32_16x16x32_bf16(a, b, acc[nf], 0, 0, 0);
            }
        }
    }
#pragma unroll
    for (int nf = 0; nf < 5; ++nf) {
        const int c = nf * 16 + fl;
        const float bb = bo[c];
#pragma unroll
        for (int j = 0; j < 4; ++j) {
            const int r = row0 + wave * 16 + fh * 4 + j;
            const float y = tanhf(acc[nf][j] + bb);
            outy[(size_t)idx[r] * DOUT_ + c] = y;
        }
    }
}

extern "C" void kernel_launch(void* const* d_in, const int* in_sizes, int n_in,
                              void* d_out, int out_size, void* d_ws, size_t ws_size,
                              hipStream_t stream) {
    const float* encoded = (const float*)d_in[0];
    const float* hidden  = (const float*)d_in[1];
    const int*   idx     = (const int*)d_in[2];
    const float* w_ih    = (const float*)d_in[3];
    const float* w_hh    = (const float*)d_in[4];
    const float* b_ih    = (const float*)d_in[5];
    const float* b_hh    = (const float*)d_in[6];
    const float* w_out   = (const float*)d_in[7];
    const float* b_out   = (const float*)d_in[8];

    float* outy = (float*)d_out;
    float* outh = outy + (size_t)B_ * DOUT_;

    ushort_t* ws    = (ushort_t*)d_ws;
    ushort_t* wihb  = ws;
    ushort_t* whhb  = wihb + (size_t)L_ * G3_ * H_;
    ushort_t* woutb = whhb + (size_t)L_ * G3_ * H_;
    ushort_t* xb0   = woutb + (size_t)DOUT_ * H_;
    ushort_t* xb1   = xb0 + (size_t)NACT_ * H_;
    ushort_t* hb    = xb1 + (size_t)NACT_ * H_;

    hipMemsetAsync(outy, 0, (size_t)B_ * DOUT_ * sizeof(float), stream);
    hipMemcpyAsync(outh, hidden, (size_t)L_ * B_ * H_ * sizeof(float),
                   hipMemcpyDeviceToDevice, stream);

    prep_convert<<<2048, 256, 0, stream>>>(w_ih, w_hh, w_out, wihb, whhb, woutb);
    prep_gather<<<2048, 256, 0, stream>>>(encoded, hidden, idx, xb0, hb);

    dim3 ggrid(16, 64);
    ushort_t* xin = xb0;
    ushort_t* xout = xb1;
    for (int i = 0; i < L_; ++i) {
        gru_layer<<<ggrid, 256, 0, stream>>>(
            xin, hb + (size_t)i * NACT_ * H_, hidden + (size_t)i * B_ * H_,
            wihb + (size_t)i * G3_ * H_, whhb + (size_t)i * G3_ * H_,
            b_ih + (size_t)i * G3_, b_hh + (size_t)i * G3_, idx,
            outh + (size_t)i * B_ * H_, xout);
        ushort_t* t = xin; xin = xout; xout = t;
    }
    head_gemm<<<64, 256, 0, stream>>>(xin, woutb, b_out, idx, outy);
}

// Round 2
// 289.104 us; speedup vs baseline: 1.5766x; 1.5766x over previous
//
#include <hip/hip_runtime.h>

typedef unsigned short ushort_t;
typedef unsigned int uint_t;
typedef __attribute__((ext_vector_type(8))) short bf16x8;
typedef __attribute__((ext_vector_type(4))) float f32x4;

constexpr int L_   = 3;
constexpr int B_   = 8192;
constexpr int H_   = 1024;
constexpr int DIN_ = 1024;
constexpr int DOUT_= 80;
constexpr int NACT_= 4096;
constexpr int G3_  = 3 * H_;

static __device__ __forceinline__ ushort_t f2bf(float f) {
    uint_t u = __float_as_uint(f);
    uint_t r = (u + 0x7FFFu + ((u >> 16) & 1u)) >> 16;
    return (ushort_t)r;
}

static __device__ __forceinline__ void gll16(const void* g, void* l) {
    __builtin_amdgcn_global_load_lds(
        (const __attribute__((address_space(1))) uint32_t*)g,
        (__attribute__((address_space(3))) uint32_t*)l, 16, 0, 0);
}

// ---------------- prep: convert weights fp32 -> bf16 ----------------
__global__ void prep_convert(const float* __restrict__ wih, const float* __restrict__ whh,
                             const float* __restrict__ wout,
                             ushort_t* __restrict__ oih, ushort_t* __restrict__ ohh,
                             ushort_t* __restrict__ oout) {
    int tid = blockIdx.x * blockDim.x + threadIdx.x;
    int nth = gridDim.x * blockDim.x;
    const int NW = L_ * G3_ * H_ / 4;
    for (int i = tid; i < NW; i += nth) {
        float4 a = ((const float4*)wih)[i];
        ushort4 o; o.x = f2bf(a.x); o.y = f2bf(a.y); o.z = f2bf(a.z); o.w = f2bf(a.w);
        ((ushort4*)oih)[i] = o;
        float4 b = ((const float4*)whh)[i];
        ushort4 p; p.x = f2bf(b.x); p.y = f2bf(b.y); p.z = f2bf(b.z); p.w = f2bf(b.w);
        ((ushort4*)ohh)[i] = p;
    }
    const int NO = DOUT_ * H_ / 4;
    for (int i = tid; i < NO; i += nth) {
        float4 a = ((const float4*)wout)[i];
        ushort4 o; o.x = f2bf(a.x); o.y = f2bf(a.y); o.z = f2bf(a.z); o.w = f2bf(a.w);
        ((ushort4*)oout)[i] = o;
    }
}

// ---------------- prep: gather x0 = encoded[idx], h_b16[l] = hidden[l][idx] ----------------
__global__ void prep_gather(const float* __restrict__ encoded, const float* __restrict__ hidden,
                            const int* __restrict__ idx,
                            ushort_t* __restrict__ x0, ushort_t* __restrict__ hb) {
    const int C4 = H_ / 4;              // 256 float4 per row
    const int PER = NACT_ * C4;         // per segment
    int tid = blockIdx.x * blockDim.x + threadIdx.x;
    int nth = gridDim.x * blockDim.x;
    int total = 4 * PER;                // seg0 = x, seg1..3 = h layers
    for (int i = tid; i < total; i += nth) {
        int seg = i / PER;
        int rem = i - seg * PER;
        int r = rem / C4, c = rem % C4;
        int gr = idx[r];
        const float* src = (seg == 0) ? (encoded + (size_t)gr * DIN_)
                                      : (hidden + ((size_t)(seg - 1) * B_ + gr) * H_);
        float4 v = ((const float4*)src)[c];
        ushort4 o; o.x = f2bf(v.x); o.y = f2bf(v.y); o.z = f2bf(v.z); o.w = f2bf(v.w);
        ushort_t* dst = (seg == 0) ? x0 : (hb + (size_t)(seg - 1) * NACT_ * H_);
        ((ushort4*)(dst + (size_t)r * H_))[c] = o;
    }
}

// ---------------- fused GRU layer: m97-structure GEMM + gate epilogue ----------------
// Tile: 128 rows x 64 gate-cols; 4 accumulator sets (r, z, n_x, n_h).
// LDS linear dest via global_load_lds; XOR slot swizzle done on the GLOBAL
// source address (inverse) + on the ds_read address (rule 21).
__global__ __launch_bounds__(256, 2) void gru_layer(
    const ushort_t* __restrict__ xb,    // [N,H] bf16 layer input
    const ushort_t* __restrict__ hb,    // [N,H] bf16 gathered hidden
    const float* __restrict__ hid_full, // [B,H] fp32 hidden[i]
    const ushort_t* __restrict__ wih,   // [3H,H] bf16
    const ushort_t* __restrict__ whh,   // [3H,H] bf16
    const float* __restrict__ bih, const float* __restrict__ bhh,
    const int* __restrict__ idx,
    float* __restrict__ out_hid,        // [B,H] fp32 (pre-copied)
    ushort_t* __restrict__ xnext)       // [N,H] bf16
{
    __shared__ ushort_t As[128 * 64];   // 16 KB, row stride 64 bf16 (128 B)
    __shared__ ushort_t Ws[192 * 64];   // 24 KB, 3 gates x 64 rows

    const int tid = threadIdx.x;
    const int bid = blockIdx.x;
    const int swz = (bid & 7) * 64 + (bid >> 3);   // XCD-chunked, bijective (512 % 8 == 0)
    const int bn = swz & 15, bm = swz >> 4;
    const int row0 = bm * 128, col0 = bn * 64;
    const int wave = tid >> 6, lane = tid & 63;
    const int wr = wave >> 1, wc = wave & 1;
    const int fl = lane & 15, fh = lane >> 4;
    const int srow = lane >> 3;                    // DMA: row-within-8 for this lane
    const int sxor = ((lane & 7) ^ srow) * 8;      // inverse-swizzled source 16B slot (ushorts)

    f32x4 accR[4][2] = {};
    f32x4 accZ[4][2] = {};
    f32x4 accN[2][4][2] = {};

#pragma unroll
    for (int ph = 0; ph < 2; ++ph) {
        const ushort_t* Asrc = ph ? hb : xb;
        const ushort_t* Wsrc = ph ? whh : wih;
        const ushort_t* abase[4];
        const ushort_t* wbase[6];
#pragma unroll
        for (int t = 0; t < 4; ++t)
            abase[t] = Asrc + (size_t)(row0 + wave * 32 + t * 8 + srow) * H_ + sxor;
#pragma unroll
        for (int t = 0; t < 6; ++t) {
            const int slot = wave * 48 + t * 8 + srow;   // global row index /8 within W region
            const int gate = slot >> 6, rowW = slot & 63;
            wbase[t] = Wsrc + (size_t)(gate * H_ + col0 + rowW) * H_ + sxor;
        }
        for (int kk = 0; kk < H_; kk += 64) {
            __syncthreads();
#pragma unroll
            for (int t = 0; t < 4; ++t)
                gll16(abase[t] + kk, &As[wave * 2048 + t * 512]);
#pragma unroll
            for (int t = 0; t < 6; ++t)
                gll16(wbase[t] + kk, &Ws[wave * 3072 + t * 512]);
            __syncthreads();
#pragma unroll
            for (int ks = 0; ks < 2; ++ks) {
                const int sl = ((ks * 4 + fh) ^ (fl & 7)) * 8;  // swizzled ds_read slot
                bf16x8 a[4];
#pragma unroll
                for (int m = 0; m < 4; ++m)
                    a[m] = *(const bf16x8*)&As[(wr * 64 + m * 16 + fl) * 64 + sl];
#pragma unroll
                for (int g = 0; g < 3; ++g) {
#pragma unroll
                    for (int n = 0; n < 2; ++n) {
                        const bf16x8 b = *(const bf16x8*)&Ws[(g * 64 + wc * 32 + n * 16 + fl) * 64 + sl];
#pragma unroll
                        for (int m = 0; m < 4; ++m) {
                            if (g == 0)
                                accR[m][n] = __builtin_amdgcn_mfma_f32_16x16x32_bf16(a[m], b, accR[m][n], 0, 0, 0);
                            else if (g == 1)
                                accZ[m][n] = __builtin_amdgcn_mfma_f32_16x16x32_bf16(a[m], b, accZ[m][n], 0, 0, 0);
                            else
                                accN[ph][m][n] = __builtin_amdgcn_mfma_f32_16x16x32_bf16(a[m], b, accN[ph][m][n], 0, 0, 0);
                        }
                    }
                }
            }
        }
    }

    // epilogue: gate math, scatter into out_hid, write bf16 x for next layer
#pragma unroll
    for (int m = 0; m < 4; ++m) {
#pragma unroll
        for (int n = 0; n < 2; ++n) {
            const int c = col0 + wc * 32 + n * 16 + fl;
            const float br_r = bih[c] + bhh[c];
            const float br_z = bih[H_ + c] + bhh[H_ + c];
            const float bi_n = bih[2 * H_ + c];
            const float bh_n = bhh[2 * H_ + c];
#pragma unroll
            for (int j = 0; j < 4; ++j) {
                const int r = row0 + wr * 64 + m * 16 + fh * 4 + j;
                const float vr = 1.f / (1.f + expf(-(accR[m][n][j] + br_r)));
                const float vz = 1.f / (1.f + expf(-(accZ[m][n][j] + br_z)));
                const float vn = tanhf(accN[0][m][n][j] + bi_n + vr * (accN[1][m][n][j] + bh_n));
                const int gr = idx[r];
                const float h0 = hid_full[(size_t)gr * H_ + c];
                const float ho = (1.f - vz) * vn + vz * h0;
                out_hid[(size_t)gr * H_ + c] = ho;
                xnext[(size_t)r * H_ + c] = f2bf(ho);
            }
        }
    }
}

// ---------------- head: y = tanh(x @ w_out^T + b_out), scatter ----------------
__global__ __launch_bounds__(256) void head_gemm(
    const ushort_t* __restrict__ xb, const ushort_t* __restrict__ wo,
    const float* __restrict__ bo, const int* __restrict__ idx,
    float* __restrict__ outy)
{
    __shared__ ushort_t Xs[64][72];
    __shared__ ushort_t Ws[80][72];
    const int tid = threadIdx.x;
    const int row0 = blockIdx.x * 64;
    const int lrow = tid >> 2, lseg = tid & 3;
    const int wave = tid >> 6, lane = tid & 63;
    const int fl = lane & 15, fh = lane >> 4;
    f32x4 acc[5] = {};

    for (int kk = 0; kk < H_; kk += 64) {
        __syncthreads();
        const ushort_t* xp = xb + (size_t)(row0 + lrow) * H_ + kk + lseg * 16;
        *(uint4*)&Xs[lrow][lseg * 16]     = *(const uint4*)xp;
        *(uint4*)&Xs[lrow][lseg * 16 + 8] = *(const uint4*)(xp + 8);
        for (int t = tid; t < 320; t += 256) {
            int r = t >> 2, s = t & 3;
            const ushort_t* wp = wo + (size_t)r * H_ + kk + s * 16;
            *(uint4*)&Ws[r][s * 16]     = *(const uint4*)wp;
            *(uint4*)&Ws[r][s * 16 + 8] = *(const uint4*)(wp + 8);
        }
        __syncthreads();
#pragma unroll
        for (int ks = 0; ks < 64; ks += 32) {
            bf16x8 a = *(const bf16x8*)&Xs[wave * 16 + fl][ks + fh * 8];
#pragma unroll
            for (int nf = 0; nf < 5; ++nf) {
                bf16x8 b = *(const bf16x8*)&Ws[nf * 16 + fl][ks + fh * 8];
                acc[nf] = __builtin_amdgcn_mfma_f32_16x16x32_bf16(a, b, acc[nf], 0, 0, 0);
            }
        }
    }
#pragma unroll
    for (int nf = 0; nf < 5; ++nf) {
        const int c = nf * 16 + fl;
        const float bb = bo[c];
#pragma unroll
        for (int j = 0; j < 4; ++j) {
            const int r = row0 + wave * 16 + fh * 4 + j;
            const float y = tanhf(acc[nf][j] + bb);
            outy[(size_t)idx[r] * DOUT_ + c] = y;
        }
    }
}

extern "C" void kernel_launch(void* const* d_in, const int* in_sizes, int n_in,
                              void* d_out, int out_size, void* d_ws, size_t ws_size,
                              hipStream_t stream) {
    const float* encoded = (const float*)d_in[0];
    const float* hidden  = (const float*)d_in[1];
    const int*   idx     = (const int*)d_in[2];
    const float* w_ih    = (const float*)d_in[3];
    const float* w_hh    = (const float*)d_in[4];
    const float* b_ih    = (const float*)d_in[5];
    const float* b_hh    = (const float*)d_in[6];
    const float* w_out   = (const float*)d_in[7];
    const float* b_out   = (const float*)d_in[8];

    float* outy = (float*)d_out;
    float* outh = outy + (size_t)B_ * DOUT_;

    ushort_t* ws    = (ushort_t*)d_ws;
    ushort_t* wihb  = ws;
    ushort_t* whhb  = wihb + (size_t)L_ * G3_ * H_;
    ushort_t* woutb = whhb + (size_t)L_ * G3_ * H_;
    ushort_t* xb0   = woutb + (size_t)DOUT_ * H_;
    ushort_t* xb1   = xb0 + (size_t)NACT_ * H_;
    ushort_t* hb    = xb1 + (size_t)NACT_ * H_;

    hipMemsetAsync(outy, 0, (size_t)B_ * DOUT_ * sizeof(float), stream);
    hipMemcpyAsync(outh, hidden, (size_t)L_ * B_ * H_ * sizeof(float),
                   hipMemcpyDeviceToDevice, stream);

    prep_convert<<<2048, 256, 0, stream>>>(w_ih, w_hh, w_out, wihb, whhb, woutb);
    prep_gather<<<2048, 256, 0, stream>>>(encoded, hidden, idx, xb0, hb);

    ushort_t* xin = xb0;
    ushort_t* xout = xb1;
    for (int i = 0; i < L_; ++i) {
        gru_layer<<<512, 256, 0, stream>>>(
            xin, hb + (size_t)i * NACT_ * H_, hidden + (size_t)i * B_ * H_,
            wihb + (size_t)i * G3_ * H_, whhb + (size_t)i * G3_ * H_,
            b_ih + (size_t)i * G3_, b_hh + (size_t)i * G3_, idx,
            outh + (size_t)i * B_ * H_, xout);
        ushort_t* t = xin; xin = xout; xout = t;
    }
    head_gemm<<<64, 256, 0, stream>>>(xin, woutb, b_out, idx, outy);
}